// Round 2
// baseline (266.733 us; speedup 1.0000x reference)
//
#include <hip/hip_runtime.h>
#include <stdint.h>

#define NROWS 16384
#define QNUM  8192
#define ED    512
#define BM    128
#define BN    128
#define KTILES 8           // K tiles of 64 elements
#define QBLKS  (QNUM / BN) // 64
#define DELTA  0.02f       // >=6 sigma of (err_i - err_j) for fp8 ranking noise
#define ESLOT  17          // 16 top2-key entries per row + 1 pad (uint2 units)

typedef int   i32x8  __attribute__((ext_vector_type(8)));   // 32 B fp8 fragment (8 VGPR)
typedef float f32x16 __attribute__((ext_vector_type(16)));  // 32x32 MFMA accumulator

// sortable key: monotone float->uint, low 13 bits replaced by q index (0..8191).
// score perturbation from clearing 13 mantissa bits <= ~6e-5 at |s|~0.1 — absorbed
// by DELTA. min-key == (min score, tie -> min idx).
static __device__ __forceinline__ unsigned enc_key(float s, unsigned idx) {
    const unsigned b = __float_as_uint(s);
    const unsigned m = (unsigned)(((int)b) >> 31) | 0x80000000u;
    return ((b ^ m) & 0xFFFFE000u) | idx;
}
// decode key -> floored float value (<= true score)
static __device__ __forceinline__ float dec_key(unsigned k) {
    const unsigned u = k & 0xFFFFE000u;
    return (u & 0x80000000u) ? __uint_as_float(u ^ 0x80000000u)
                             : __uint_as_float(~u);
}

static __device__ __forceinline__ void ins3k(unsigned& v1, unsigned& v2, unsigned& v3,
                                             unsigned k) {
    const bool b1 = k < v1, b2 = k < v2, b3 = k < v3;
    v3 = b2 ? v2 : (b3 ? k : v3);
    v2 = b1 ? v1 : (b2 ? k : v2);
    v1 = b1 ? k : v1;
}

// ---------------- fused prep: numpy-pairwise sumsq + fp32->fp8 MX-granule layout ----------------
// Sumsq phase is the R2-verified numpy-pairwise tree, verbatim. fp8 phase emits the
// 32x32x64 f8f6f4 fragment layout: 32-row tiles (rt), 64-elem k-tiles (kt); lane
// l = kb*32 + rr holds row rr's bytes k = kt*64 + kb*32 .. +32, stored contiguously
// as one 32 B block at index G = (rt*8 + kt)*64 + kb*32 + rr.
#define SROWS 32
#define SSTRIDE 520
__global__ __launch_bounds__(256) void k_prep_sumsq(const float* __restrict__ src,
                                                    float* __restrict__ dst_sq,
                                                    unsigned long long* __restrict__ dst8,
                                                    float scale) {
    __shared__ float ld[SROWS * SSTRIDE];
    const int t = threadIdx.x;
    const size_t base = (size_t)blockIdx.x * SROWS * ED;
    #pragma unroll
    for (int k = 0; k < 16; ++k) {
        int u = k * 256 + t;
        int row = u >> 7;
        int c4  = u & 127;
        float4 v = ((const float4*)(src + base))[u];
        float* d = ld + row * SSTRIDE + c4 * 4;
        d[0] = v.x; d[1] = v.y; d[2] = v.z; d[3] = v.w;
    }
    __syncthreads();
    const int row = t >> 3, j = t & 7;
    const float* a = ld + row * SSTRIDE;
    float B[4];
    #pragma unroll
    for (int b = 0; b < 4; ++b) {
        const float* p = a + b * 128 + j;
        float r = __fmul_rn(p[0], p[0]);
        #pragma unroll
        for (int i = 1; i < 16; ++i) {
            float q = p[8 * i];
            r = __fadd_rn(r, __fmul_rn(q, q));
        }
        float t1 = __fadd_rn(r,  __shfl_xor(r,  1, 64));
        float t2 = __fadd_rn(t1, __shfl_xor(t1, 2, 64));
        B[b]     = __fadd_rn(t2, __shfl_xor(t2, 4, 64));
    }
    if (j == 0)
        dst_sq[(size_t)blockIdx.x * SROWS + row] =
            __fadd_rn(__fadd_rn(B[0], B[1]), __fadd_rn(B[2], B[3]));

    // fp8 phase: thread (row, j) owns k-tile kt = j (64 elems = two 32 B blocks)
    #pragma unroll
    for (int kb = 0; kb < 2; ++kb) {
        const float* e = a + j * 64 + kb * 32;
        unsigned d[8];
        #pragma unroll
        for (int p = 0; p < 8; ++p) {
            int w0 = __builtin_amdgcn_cvt_pk_fp8_f32(e[4*p+0] * scale, e[4*p+1] * scale, 0,  false);
            w0     = __builtin_amdgcn_cvt_pk_fp8_f32(e[4*p+2] * scale, e[4*p+3] * scale, w0, true);
            d[p] = (unsigned)w0;
        }
        const size_t G = ((size_t)(blockIdx.x * 8 + j) * 64 + kb * 32 + row);
        uint4* dp = (uint4*)dst8 + G * 2;
        dp[0] = make_uint4(d[0], d[1], d[2], d[3]);
        dp[1] = make_uint4(d[4], d[5], d[6], d[7]);
    }
}

// ---------------- phase 1: MX-scaled fp8 MFMA (unit scales) + sortable-key top-2 epilogue ----------------
// 32x32x64 f8f6f4 with e8m0 scale 0x7F (=1.0): dot products numerically identical to
// the verified 16x16x32 fp8 path, at 2.14x the MFMA rate. Per wave: 2x2 tiles of
// 32x32, 8 K-steps, 32 MFMA (~550 cyc) vs 256 (~1240 cyc) before.
// C/D layout (HW-verified, shape-determined): col = lane&31,
// row = (reg&3) + 8*(reg>>2) + 4*(lane>>5).
__global__ __launch_bounds__(256, 2) void k_gemm_top2(
        const uint4* __restrict__ xb,   // MX-granule fp8 (32 B per lane-block)
        const uint4* __restrict__ wb,   // MX-granule fp8 (x512)
        const float* __restrict__ wsqf,
        uint4* __restrict__ p3) {
    __shared__ uint2 ered[BM * ESLOT];   // 17,408 B

    const int t  = threadIdx.x;
    const int wv = t >> 6;
    const int l  = t & 63;
    const int h  = l >> 5;   // lane half -> row +4 / k-block
    const int cn = l & 31;   // MFMA col within 32-col tile
    const int RB = (wv >> 1) * 64;
    const int CB = (wv & 1) * 64;

    // XCD-aware swizzle (R6+): id%8 = XCD; each XCD keeps 8 q-panels L2-hot.
    const int id = blockIdx.x;
    const int qb = (id & 7) * 8 + ((id >> 3) & 7);  // 0..63
    const int rb = id >> 6;                          // 0..127
    const int q0 = qb * BN;
    const int r0 = rb * BM;

    f32x16 acc[2][2];
    #pragma unroll
    for (int i = 0; i < 2; ++i)
        #pragma unroll
        for (int j = 0; j < 2; ++j)
            #pragma unroll
            for (int r = 0; r < 16; ++r)
                acc[i][j][r] = 0.f;

    const int rt0 = (r0 + RB) >> 5;   // two consecutive 32-row A tiles
    const int qt0 = (q0 + CB) >> 5;   // two consecutive 32-col B tiles
    const uint4* ga = xb + ((size_t)(rt0 * 8) * 64 + l) * 2;
    const uint4* gb = wb + ((size_t)(qt0 * 8) * 64 + l) * 2;

    i32x8 Af[2][2], Bf[2][2];   // [buf][tile]

#define LD32(dst, p, blk) do {                                   \
        const uint4 u0 = (p)[(size_t)(blk) * 128];               \
        const uint4 u1 = (p)[(size_t)(blk) * 128 + 1];           \
        dst = (i32x8){(int)u0.x, (int)u0.y, (int)u0.z, (int)u0.w,\
                      (int)u1.x, (int)u1.y, (int)u1.z, (int)u1.w};\
    } while (0)

    #pragma unroll
    for (int i = 0; i < 2; ++i) LD32(Af[0][i], ga, i * 8);
    #pragma unroll
    for (int j = 0; j < 2; ++j) LD32(Bf[0][j], gb, j * 8);

    #pragma unroll
    for (int kt = 0; kt < KTILES; ++kt) {
        const int cur = kt & 1, nxt = cur ^ 1;
        if (kt + 1 < KTILES) {   // depth-1 prefetch: next tile in flight across MFMAs
            #pragma unroll
            for (int i = 0; i < 2; ++i) LD32(Af[nxt][i], ga, i * 8 + kt + 1);
            #pragma unroll
            for (int j = 0; j < 2; ++j) LD32(Bf[nxt][j], gb, j * 8 + kt + 1);
        }
        __builtin_amdgcn_s_setprio(1);
        #pragma unroll
        for (int i = 0; i < 2; ++i)
            #pragma unroll
            for (int j = 0; j < 2; ++j)
                acc[i][j] = __builtin_amdgcn_mfma_scale_f32_32x32x64_f8f6f4(
                        Af[cur][i], Bf[cur][j], acc[i][j],
                        0, 0,                       // cbsz = fp8, blgp = fp8
                        0, 0x7F7F7F7F,              // scale A: e8m0 1.0
                        0, 0x7F7F7F7F);             // scale B: e8m0 1.0
        __builtin_amdgcn_s_setprio(0);
    }

    // epilogue: score = wsq - 2*dot*2^-9 (w scaled by 2^9 at prep)
    float wsqv[2]; unsigned kidx[2];
    #pragma unroll
    for (int j = 0; j < 2; ++j) {
        const int qj = q0 + CB + j * 32 + cn;
        wsqv[j] = wsqf[qj];
        kidx[j] = (unsigned)qj;
    }

    #pragma unroll
    for (int i = 0; i < 2; ++i) {
        #pragma unroll
        for (int rg = 0; rg < 4; ++rg) {
            #pragma unroll
            for (int rr = 0; rr < 4; ++rr) {
                const int reg = rg * 4 + rr;
                const unsigned k0 = enc_key(fmaf(-0.00390625f, acc[i][0][reg], wsqv[0]), kidx[0]);
                const unsigned k1 = enc_key(fmaf(-0.00390625f, acc[i][1][reg], wsqv[1]), kidx[1]);
                unsigned v1 = min(k0, k1);
                unsigned v2 = max(k0, k1);
                // xor-8 merge: top2 of {self, lane^8}
                {
                    const unsigned o1 = __shfl_xor((int)v1, 8, 64);
                    const unsigned o2 = __shfl_xor((int)v2, 8, 64);
                    const unsigned nv1 = min(v1, o1);
                    v2 = min(max(v1, o1), min(v2, o2));
                    v1 = nv1;
                }
                // xor-16 merge: top2 of 4-lane group {l, l^8, l^16, l^24}
                {
                    const unsigned o1 = __shfl_xor((int)v1, 16, 64);
                    const unsigned o2 = __shfl_xor((int)v2, 16, 64);
                    const unsigned nv1 = min(v1, o1);
                    v2 = min(max(v1, o1), min(v2, o2));
                    v1 = nv1;
                }
                if ((l & 24) == 0) {   // one representative per 4-lane group, per half
                    const int row = RB + i * 32 + rr + 8 * rg + 4 * h;
                    ered[row * ESLOT + (wv & 1) * 8 + (l & 7)] = make_uint2(v1, v2);
                }
            }
        }
    }
    __syncthreads();
    if (t < BM) {
        const uint2* e = &ered[t * ESLOT];
        unsigned v1 = 0xFFFFFFFFu, v2 = 0xFFFFFFFFu, v3 = 0xFFFFFFFFu;
        #pragma unroll
        for (int k = 0; k < 16; ++k) {
            const uint2 E = e[k];
            ins3k(v1, v2, v3, E.x);
            ins3k(v1, v2, v3, E.y);
        }
        p3[(size_t)(r0 + t) * QBLKS + qb] = make_uint4(v1, v2, v3, 0xFFFFFFFFu);
    }
}

// ---------------- phase 2: fp32-emulated (numpy semantics) rescore + gather ----------------
__global__ __launch_bounds__(256) void k_rescore(
        const uint4* __restrict__ p3,
        const float* __restrict__ x,
        const float* __restrict__ wt,
        const float* __restrict__ wsqf,
        const float* __restrict__ xsqf,
        float* __restrict__ outq,
        float* __restrict__ outi) {
    const int wv = threadIdx.x >> 6, l = threadIdx.x & 63;
    const int row = blockIdx.x * 4 + wv;

    const uint4 P = p3[(size_t)row * QBLKS + l];
    unsigned vk[3] = { P.x, P.y, P.z };

    unsigned gk = vk[0];
    #pragma unroll
    for (int m = 1; m < 64; m <<= 1) gk = min(gk, (unsigned)__shfl_xor((int)gk, m, 64));
    // threshold in key space: decode floored gm, add DELTA, re-encode, idx bits = 1s
    const float tf = dec_key(gk) + DELTA;
    const unsigned tb = __float_as_uint(tf);
    const unsigned tm = (unsigned)(((int)tb) >> 31) | 0x80000000u;
    const unsigned thrkey = (tb ^ tm) | 0x1FFFu;

    const float4* xp = (const float4*)(x + (size_t)row * ED + l * 8);
    const float4 xa = xp[0], xbv = xp[1];
    const float xsq = xsqf[row];

    float bestv = 3.4e38f; int bestq = 0x7fffffff;
    #pragma unroll
    for (int k = 0; k < 3; ++k) {
        unsigned long long mm = __ballot(vk[k] <= thrkey);
        while (mm) {
            const int ln = __ffsll(mm) - 1;
            mm &= mm - 1;
            const int q = __shfl((int)vk[k], ln, 64) & 0x1FFF;
            const float4* wp = (const float4*)(wt + (size_t)q * ED + l * 8);
            const float4 wa = wp[0], wbv = wp[1];
            double d = (double)xa.x * wa.x + (double)xa.y * wa.y
                     + (double)xa.z * wa.z + (double)xa.w * wa.w
                     + (double)xbv.x * wbv.x + (double)xbv.y * wbv.y
                     + (double)xbv.z * wbv.z + (double)xbv.w * wbv.w;
            #pragma unroll
            for (int m = 1; m < 64; m <<= 1) d += __shfl_xor(d, m, 64);
            // numpy fp32 semantics: fl32( fl32(x_sq - 2*dot) + w_sq ), first-occurrence argmin
            const float dotf = (float)d;
            const float t1 = __fadd_rn(xsq, __fmul_rn(-2.0f, dotf));
            const float sc = __fadd_rn(t1, wsqf[q]);
            if (sc < bestv || (sc == bestv && q < bestq)) { bestv = sc; bestq = q; }
        }
    }
    const float4* wp = (const float4*)(wt + (size_t)bestq * ED + l * 8);
    float4* op = (float4*)(outq + (size_t)row * ED + l * 8);
    op[0] = wp[0]; op[1] = wp[1];
    if (l == 0) outi[row] = (float)bestq;
}

extern "C" void kernel_launch(void* const* d_in, const int* in_sizes, int n_in,
                              void* d_out, int out_size, void* d_ws, size_t ws_size,
                              hipStream_t stream) {
    (void)in_sizes; (void)n_in; (void)out_size; (void)ws_size;
    const float* x  = (const float*)d_in[0];
    const float* wt = (const float*)d_in[1];

    char* ws = (char*)d_ws;
    unsigned long long* xb8 = (unsigned long long*)ws;               //  8,388,608 B
    unsigned long long* wb8 = (unsigned long long*)(ws + 8388608);   //  4,194,304 B
    float* wsqf = (float*)(ws + 12582912);                           //     32,768 B
    float* xsqf = (float*)(ws + 12615680);                           //     65,536 B
    uint4* p3   = (uint4*)(ws + 12681216);                           // 16,777,216 B (end ~29.5 MB)

    float* outq = (float*)d_out;
    float* outi = outq + (size_t)NROWS * ED;

    k_prep_sumsq<<<NROWS / SROWS, 256, 0, stream>>>(x,  xsqf, xb8, 1.0f);
    k_prep_sumsq<<<QNUM  / SROWS, 256, 0, stream>>>(wt, wsqf, wb8, 512.0f);  // 2^9 lifts w out of e4m3 subnormals
    k_gemm_top2<<<8192, 256, 0, stream>>>((const uint4*)xb8, (const uint4*)wb8, wsqf, p3);
    k_rescore<<<4096, 256, 0, stream>>>(p3, x, wt, wsqf, xsqf, outq, outi);
}